// Round 1
// baseline (95.663 us; speedup 1.0000x reference)
//
#include <hip/hip_runtime.h>
#include <math.h>

#define BB 8
#define NN 256
#define F_IN 64
#define HID 128
constexpr float NEG_SLOPE = 0.2f;

// ---------------------------------------------------------------------------
// Kernel A: per (b,n) compute s = leaky(x)·a_src, d = leaky(x)·a_dst where
// x = W_lin @ src[b,n].  One block of 128 threads per (b,n); thread h owns
// one hidden unit.  Extra block (blockIdx == BB*NN) computes the scalar
// coef = W_edge · a_edge.
// Output layout in ws:  sd[0..BN)   = s
//                       sd[BN..2BN) = d
//                       sd[2BN]     = coef
// ---------------------------------------------------------------------------
__global__ void __launch_bounds__(128) attn_sd_kernel(
    const float* __restrict__ src, const float* __restrict__ W_lin,
    const float* __restrict__ a_src, const float* __restrict__ a_dst,
    const float* __restrict__ W_edge, const float* __restrict__ a_edge,
    float* __restrict__ sd)
{
    const int blk = blockIdx.x;
    const int t = threadIdx.x;
    const int BN = BB * NN;

    if (blk == BN) {
        // coef = dot(W_edge[:,0], a_edge[:,0]) over EDGE_F=64
        float v = (t < 64) ? W_edge[t] * a_edge[t] : 0.0f;
        #pragma unroll
        for (int off = 32; off > 0; off >>= 1) v += __shfl_down(v, off);
        if (t == 0) sd[2 * BN] = v;
        return;
    }

    __shared__ float s_src[F_IN];
    if (t < F_IN) s_src[t] = src[blk * F_IN + t];
    __syncthreads();

    // x_h = dot(W_lin[h,:], src_row)
    const float4* w4 = reinterpret_cast<const float4*>(W_lin + t * F_IN);
    float acc = 0.0f;
    #pragma unroll
    for (int f4 = 0; f4 < F_IN / 4; ++f4) {
        float4 w = w4[f4];
        acc += w.x * s_src[f4 * 4 + 0] + w.y * s_src[f4 * 4 + 1]
             + w.z * s_src[f4 * 4 + 2] + w.w * s_src[f4 * 4 + 3];
    }
    float x = acc > 0.0f ? acc : NEG_SLOPE * acc;   // leaky_relu
    float sv = x * a_src[t];
    float dv = x * a_dst[t];

    // block-reduce 128 values (2 waves of 64)
    #pragma unroll
    for (int off = 32; off > 0; off >>= 1) {
        sv += __shfl_down(sv, off);
        dv += __shfl_down(dv, off);
    }
    __shared__ float red[4];
    const int wave = t >> 6, lane = t & 63;
    if (lane == 0) { red[wave * 2 + 0] = sv; red[wave * 2 + 1] = dv; }
    __syncthreads();
    if (t == 0) {
        sd[blk]      = red[0] + red[2];
        sd[BN + blk] = red[1] + red[3];
    }
}

// ---------------------------------------------------------------------------
// Kernel B: one block of 256 threads per (b,i) row.  Thread j computes
// e[j] = s[i] + d[j] + ||src_i - src_j|| * coef * adj[b,i,j], a = e * mask,
// then block softmax over j, coalesced store.
// ---------------------------------------------------------------------------
__global__ void __launch_bounds__(256) attn_row_kernel(
    const float* __restrict__ src, const int* __restrict__ adj,
    const int* __restrict__ mask, const float* __restrict__ sd,
    float* __restrict__ out)
{
    const int blk = blockIdx.x;          // b*NN + i
    const int b = blk >> 8;              // NN == 256
    const int j = threadIdx.x;
    const int BN = BB * NN;

    __shared__ float s_i[F_IN];
    if (j < F_IN) s_i[j] = src[blk * F_IN + j];
    __syncthreads();

    const float coef = sd[2 * BN];
    const float si   = sd[blk];
    const float dj   = sd[BN + b * NN + j];

    // ||src_i - src_j||^2 over 64 features (exact 0 at i==j)
    const float4* sj4 = reinterpret_cast<const float4*>(src + (b * NN + j) * F_IN);
    float sq = 0.0f;
    #pragma unroll
    for (int f4 = 0; f4 < F_IN / 4; ++f4) {
        float4 v = sj4[f4];
        float d0 = s_i[f4 * 4 + 0] - v.x;
        float d1 = s_i[f4 * 4 + 1] - v.y;
        float d2 = s_i[f4 * 4 + 2] - v.z;
        float d3 = s_i[f4 * 4 + 3] - v.w;
        sq += d0 * d0 + d1 * d1 + d2 * d2 + d3 * d3;
    }
    const float nrm = sq > 0.0f ? sqrtf(sq) : 0.0f;

    const float e = si + dj + nrm * coef * (float)adj[blk * NN + j];
    const float a = e * (float)mask[blk * NN + j];

    // --- block softmax over 256 threads (4 waves of 64) ---
    __shared__ float red[4];
    __shared__ float bcast;

    float m = a;
    #pragma unroll
    for (int off = 32; off > 0; off >>= 1) m = fmaxf(m, __shfl_down(m, off));
    const int wave = j >> 6, lane = j & 63;
    if (lane == 0) red[wave] = m;
    __syncthreads();
    if (j == 0) bcast = fmaxf(fmaxf(red[0], red[1]), fmaxf(red[2], red[3]));
    __syncthreads();
    const float rowmax = bcast;

    const float ex = expf(a - rowmax);
    float ssum = ex;
    #pragma unroll
    for (int off = 32; off > 0; off >>= 1) ssum += __shfl_down(ssum, off);
    __syncthreads();                 // red[] reuse hazard
    if (lane == 0) red[wave] = ssum;
    __syncthreads();
    if (j == 0) bcast = 1.0f / (red[0] + red[1] + red[2] + red[3]);
    __syncthreads();

    out[blk * NN + j] = ex * bcast;
}

extern "C" void kernel_launch(void* const* d_in, const int* in_sizes, int n_in,
                              void* d_out, int out_size, void* d_ws, size_t ws_size,
                              hipStream_t stream) {
    const float* src    = (const float*)d_in[0];
    const int*   adj    = (const int*)  d_in[1];
    const int*   mask   = (const int*)  d_in[2];
    const float* W_lin  = (const float*)d_in[3];
    const float* a_src  = (const float*)d_in[4];
    const float* a_dst  = (const float*)d_in[5];
    const float* W_edge = (const float*)d_in[6];
    const float* a_edge = (const float*)d_in[7];
    float* out = (float*)d_out;
    float* sd  = (float*)d_ws;   // 2*BB*NN + 1 floats

    attn_sd_kernel<<<BB * NN + 1, 128, 0, stream>>>(src, W_lin, a_src, a_dst,
                                                    W_edge, a_edge, sd);
    attn_row_kernel<<<BB * NN, 256, 0, stream>>>(src, adj, mask, sd, out);
}

// Round 2
// 82.340 us; speedup vs baseline: 1.1618x; 1.1618x over previous
//
#include <hip/hip_runtime.h>
#include <math.h>

#define BB 8
#define NN 256
#define F_IN 64
#define HID 128
constexpr float NEG_SLOPE = 0.2f;
// ws layout: sd[0..2048) = s,  sd[2048..4096) = d,  sd[4096] = coef
#define BN (BB * NN)

// ---------------------------------------------------------------------------
// Kernel A: 2 nodes per 256-thread block. W_lin staged transposed in LDS
// (WT[f][h], stride 129 -> conflict-free reads). Threads 0-127 -> node 2*blk,
// threads 128-255 -> node 2*blk+1. Block 1024 computes coef = W_edge . a_edge.
// ---------------------------------------------------------------------------
__global__ void __launch_bounds__(256) attn_sd_kernel(
    const float* __restrict__ src, const float* __restrict__ W_lin,
    const float* __restrict__ a_src, const float* __restrict__ a_dst,
    const float* __restrict__ W_edge, const float* __restrict__ a_edge,
    float* __restrict__ sd)
{
    const int blk = blockIdx.x;
    const int t = threadIdx.x;

    if (blk == BN / 2) {
        float v = (t < 64) ? W_edge[t] * a_edge[t] : 0.0f;
        if (t < 64) {
            #pragma unroll
            for (int off = 32; off > 0; off >>= 1) v += __shfl_down(v, off);
            if (t == 0) sd[2 * BN] = v;
        }
        return;
    }

    __shared__ float WT[F_IN * 129];   // WT[f*129 + h] = W_lin[h][f]
    __shared__ float s_src[2][F_IN];
    __shared__ float red[4][2];

    // stage W_lin transposed: 2048 float4s, 8 per thread, coalesced reads
    #pragma unroll
    for (int k = 0; k < 8; ++k) {
        int idx4 = t + k * 256;            // [0, 2048)
        int h = idx4 >> 4;                 // 16 float4 per 64-float row
        int f4 = idx4 & 15;
        float4 w = reinterpret_cast<const float4*>(W_lin)[idx4];
        WT[(4 * f4 + 0) * 129 + h] = w.x;
        WT[(4 * f4 + 1) * 129 + h] = w.y;
        WT[(4 * f4 + 2) * 129 + h] = w.z;
        WT[(4 * f4 + 3) * 129 + h] = w.w;
    }
    // stage the 2 src rows (128 floats), coalesced
    if (t < 2 * F_IN) s_src[t >> 6][t & 63] = src[blk * (2 * F_IN) + t];
    __syncthreads();

    const int half = t >> 7;               // which node
    const int h = t & 127;                 // hidden unit
    float acc = 0.0f;
    #pragma unroll
    for (int f = 0; f < F_IN; ++f)
        acc = fmaf(WT[f * 129 + h], s_src[half][f], acc);   // bank-free + broadcast
    float x = acc > 0.0f ? acc : NEG_SLOPE * acc;
    float sv = x * a_src[h];
    float dv = x * a_dst[h];

    #pragma unroll
    for (int off = 32; off > 0; off >>= 1) {
        sv += __shfl_down(sv, off);
        dv += __shfl_down(dv, off);
    }
    const int wave = t >> 6, lane = t & 63;
    if (lane == 0) { red[wave][0] = sv; red[wave][1] = dv; }
    __syncthreads();
    if (t == 0) {
        sd[2 * blk]      = red[0][0] + red[1][0];
        sd[BN + 2 * blk] = red[0][1] + red[1][1];
    }
    if (t == 128) {
        sd[2 * blk + 1]      = red[2][0] + red[3][0];
        sd[BN + 2 * blk + 1] = red[2][1] + red[3][1];
    }
}

// ---------------------------------------------------------------------------
// Kernel B: 4 rows per 256-thread block (grid 512). Batch panel staged
// transposed in LDS: pT[f*257 + n] = src[b][n][f]. Lane j caches its own
// row in registers; per (row, f): one uniform broadcast ds_read + fma.
// ---------------------------------------------------------------------------
__global__ void __launch_bounds__(256) attn_row_kernel(
    const float* __restrict__ src, const int* __restrict__ adj,
    const int* __restrict__ mask, const float* __restrict__ sd,
    float* __restrict__ out)
{
    const int blk = blockIdx.x;            // rows 4*blk .. 4*blk+3
    const int j = threadIdx.x;
    const int b = blk >> 6;                // 64 blocks per batch

    __shared__ float pT[F_IN * 257];       // 65.8 KB
    __shared__ float redm[4], reds[4];
    __shared__ float bc[2];

    const float* srcb = src + b * NN * F_IN;
    #pragma unroll
    for (int k = 0; k < 16; ++k) {
        int idx4 = j + k * 256;            // [0, 4096)
        int n = idx4 >> 4;
        int f4 = idx4 & 15;
        float4 v = reinterpret_cast<const float4*>(srcb)[idx4];
        pT[(4 * f4 + 0) * 257 + n] = v.x;
        pT[(4 * f4 + 1) * 257 + n] = v.y;
        pT[(4 * f4 + 2) * 257 + n] = v.z;
        pT[(4 * f4 + 3) * 257 + n] = v.w;
    }
    __syncthreads();

    // cache own row j in registers (64 VGPRs), conflict-free (2-way)
    float pj[F_IN];
    #pragma unroll
    for (int f = 0; f < F_IN; ++f) pj[f] = pT[f * 257 + j];

    const float dj   = sd[BN + b * NN + j];
    const float coef = sd[2 * BN];
    const int wave = j >> 6, lane = j & 63;

    for (int r = 0; r < 4; ++r) {
        const int grow = blk * 4 + r;      // global row index (b*NN + i)
        const int il = grow & (NN - 1);    // i within batch
        const float si = sd[grow];

        float sq = 0.0f;
        #pragma unroll
        for (int f = 0; f < F_IN; ++f) {
            float d = pT[f * 257 + il] - pj[f];   // broadcast - register
            sq = fmaf(d, d, sq);
        }
        const float nrm = sq > 0.0f ? sqrtf(sq) : 0.0f;

        const float e = si + dj + nrm * coef * (float)adj[grow * NN + j];
        const float a = e * (float)mask[grow * NN + j];

        // block softmax over 256 lanes
        float m = a;
        #pragma unroll
        for (int off = 32; off > 0; off >>= 1) m = fmaxf(m, __shfl_down(m, off));
        if (lane == 0) redm[wave] = m;
        __syncthreads();
        if (j == 0) bc[0] = fmaxf(fmaxf(redm[0], redm[1]), fmaxf(redm[2], redm[3]));
        __syncthreads();
        const float ex = expf(a - bc[0]);

        float ssum = ex;
        #pragma unroll
        for (int off = 32; off > 0; off >>= 1) ssum += __shfl_down(ssum, off);
        if (lane == 0) reds[wave] = ssum;
        __syncthreads();
        if (j == 0) bc[1] = 1.0f / (reds[0] + reds[1] + reds[2] + reds[3]);
        __syncthreads();

        out[grow * NN + j] = ex * bc[1];
    }
}

extern "C" void kernel_launch(void* const* d_in, const int* in_sizes, int n_in,
                              void* d_out, int out_size, void* d_ws, size_t ws_size,
                              hipStream_t stream) {
    const float* src    = (const float*)d_in[0];
    const int*   adj    = (const int*)  d_in[1];
    const int*   mask   = (const int*)  d_in[2];
    const float* W_lin  = (const float*)d_in[3];
    const float* a_src  = (const float*)d_in[4];
    const float* a_dst  = (const float*)d_in[5];
    const float* W_edge = (const float*)d_in[6];
    const float* a_edge = (const float*)d_in[7];
    float* out = (float*)d_out;
    float* sd  = (float*)d_ws;   // 2*BN + 1 floats

    attn_sd_kernel<<<BN / 2 + 1, 256, 0, stream>>>(src, W_lin, a_src, a_dst,
                                                   W_edge, a_edge, sd);
    attn_row_kernel<<<BN / 4, 256, 0, stream>>>(src, adj, mask, sd, out);
}

// Round 3
// 79.388 us; speedup vs baseline: 1.2050x; 1.0372x over previous
//
#include <hip/hip_runtime.h>
#include <math.h>

#define BB 8
#define NN 256
#define F_IN 64
#define HID 128
constexpr float NEG_SLOPE = 0.2f;
#define BN (BB * NN)
// ws layout: sd[0..BN) = s, sd[BN..2BN) = d, sd[2BN] = coef

// ---------------------------------------------------------------------------
// Kernel A: 8 nodes per 256-thread block (grid 257). W_lin staged transposed
// once per block (WT[f][h], stride 129 -> 2-way/free reads); the 8 src rows
// staged transposed (sT[f][n]) so each thread's inner loop is:
//   1 b32 WT read + 1 uniform-broadcast b128 sT read + 4 FMA.
// Thread t: h = t&127, g = t>>7 -> nodes g*4..g*4+3.
// Block 256 computes coef = W_edge . a_edge.
// ---------------------------------------------------------------------------
__global__ void __launch_bounds__(256) attn_sd_kernel(
    const float* __restrict__ src, const float* __restrict__ W_lin,
    const float* __restrict__ a_src, const float* __restrict__ a_dst,
    const float* __restrict__ W_edge, const float* __restrict__ a_edge,
    float* __restrict__ sd)
{
    const int blk = blockIdx.x;
    const int t = threadIdx.x;

    if (blk == BN / 8) {
        if (t < 64) {
            float v = W_edge[t] * a_edge[t];
            #pragma unroll
            for (int off = 32; off > 0; off >>= 1) v += __shfl_xor(v, off);
            if (t == 0) sd[2 * BN] = v;
        }
        return;
    }

    __shared__ float WT[F_IN][129];   // WT[f][h] = W_lin[h][f]
    __shared__ float sT[F_IN][8];     // sT[f][n] = src[nb+n][f]
    __shared__ float red[4][8];       // per-wave partials: 4 nodes x {s,d}

    // stage W_lin transposed: 2048 float4s, 8 per thread, coalesced global
    #pragma unroll
    for (int k = 0; k < 8; ++k) {
        int idx4 = t + k * 256;            // [0, 2048)
        int h = idx4 >> 4;                 // 16 float4 per 64-float row
        int f4 = idx4 & 15;
        float4 w = reinterpret_cast<const float4*>(W_lin)[idx4];
        WT[4 * f4 + 0][h] = w.x;
        WT[4 * f4 + 1][h] = w.y;
        WT[4 * f4 + 2][h] = w.z;
        WT[4 * f4 + 3][h] = w.w;
    }
    // stage 8 src rows transposed (512 floats, 2 per thread, coalesced)
    const int nb = blk * 8;
    #pragma unroll
    for (int k = 0; k < 2; ++k) {
        int idx = t + k * 256;
        int n = idx >> 6, f = idx & 63;
        sT[f][n] = src[(nb + n) * F_IN + f];
    }
    __syncthreads();

    const int h = t & 127;
    const int g = t >> 7;                  // node group (0: nodes 0-3, 1: 4-7)
    float acc0 = 0.f, acc1 = 0.f, acc2 = 0.f, acc3 = 0.f;
    #pragma unroll
    for (int f = 0; f < F_IN; ++f) {
        float w = WT[f][h];                            // 2-way, free
        float4 s = *reinterpret_cast<const float4*>(&sT[f][g * 4]); // uniform bcast
        acc0 = fmaf(w, s.x, acc0);
        acc1 = fmaf(w, s.y, acc1);
        acc2 = fmaf(w, s.z, acc2);
        acc3 = fmaf(w, s.w, acc3);
    }
    const float as = a_src[h], ad = a_dst[h];
    float v[8];
    {
        float x0 = acc0 > 0.f ? acc0 : NEG_SLOPE * acc0;
        float x1 = acc1 > 0.f ? acc1 : NEG_SLOPE * acc1;
        float x2 = acc2 > 0.f ? acc2 : NEG_SLOPE * acc2;
        float x3 = acc3 > 0.f ? acc3 : NEG_SLOPE * acc3;
        v[0] = x0 * as; v[1] = x1 * as; v[2] = x2 * as; v[3] = x3 * as;
        v[4] = x0 * ad; v[5] = x1 * ad; v[6] = x2 * ad; v[7] = x3 * ad;
    }
    // wave butterfly reduce (all 8 values)
    #pragma unroll
    for (int off = 32; off > 0; off >>= 1) {
        #pragma unroll
        for (int q = 0; q < 8; ++q) v[q] += __shfl_xor(v[q], off);
    }
    const int wave = t >> 6, lane = t & 63;
    if (lane == 0) {
        #pragma unroll
        for (int q = 0; q < 8; ++q) red[wave][q] = v[q];
    }
    __syncthreads();
    if (t == 0) {                          // nodes nb+0..3 (waves 0+1)
        #pragma unroll
        for (int n = 0; n < 4; ++n) {
            sd[nb + n]      = red[0][n]     + red[1][n];
            sd[BN + nb + n] = red[0][4 + n] + red[1][4 + n];
        }
    }
    if (t == 128) {                        // nodes nb+4..7 (waves 2+3)
        #pragma unroll
        for (int n = 0; n < 4; ++n) {
            sd[nb + 4 + n]      = red[2][n]     + red[3][n];
            sd[BN + nb + 4 + n] = red[2][4 + n] + red[3][4 + n];
        }
    }
}

// ---------------------------------------------------------------------------
// Kernel B: 4 rows per 256-thread block (grid 512, 2 blocks/CU). Batch panel
// staged ROW-MAJOR with stride 65: staging writes <=2-way, own-row reads
// (j+f)%32 2-way/free, row-i reads uniform broadcast. Butterfly shfl_xor
// reductions (no serialized lane-0 combine), 3 barriers/row, __expf.
// ---------------------------------------------------------------------------
__global__ void __launch_bounds__(256) attn_row_kernel(
    const float* __restrict__ src, const int* __restrict__ adj,
    const int* __restrict__ mask, const float* __restrict__ sd,
    float* __restrict__ out)
{
    const int blk = blockIdx.x;            // rows 4*blk .. 4*blk+3
    const int j = threadIdx.x;
    const int b = blk >> 6;                // 64 blocks per batch

    __shared__ float pT[NN][65];           // 66.6 KB -> 2 blocks/CU
    __shared__ float redm[4], reds[4];

    const float* srcb = src + b * NN * F_IN;
    #pragma unroll
    for (int k = 0; k < 16; ++k) {
        int idx4 = j + k * 256;            // [0, 4096)
        int n = idx4 >> 4;
        int f4 = idx4 & 15;
        float4 v = reinterpret_cast<const float4*>(srcb)[idx4];
        pT[n][4 * f4 + 0] = v.x;
        pT[n][4 * f4 + 1] = v.y;
        pT[n][4 * f4 + 2] = v.z;
        pT[n][4 * f4 + 3] = v.w;
    }
    __syncthreads();

    // cache own row j in registers (64 VGPRs); banks (j+f)%32 -> 2-way, free
    float pj[F_IN];
    #pragma unroll
    for (int f = 0; f < F_IN; ++f) pj[f] = pT[j][f];

    const float dj   = sd[BN + b * NN + j];
    const float coef = sd[2 * BN];
    const int wave = j >> 6, lane = j & 63;

    for (int r = 0; r < 4; ++r) {
        const int grow = blk * 4 + r;      // b*NN + i
        const int il = grow & (NN - 1);
        const float si = sd[grow];

        float sq = 0.0f;
        #pragma unroll
        for (int f = 0; f < F_IN; ++f) {
            float d = pT[il][f] - pj[f];   // uniform broadcast - register
            sq = fmaf(d, d, sq);
        }
        const float nrm = sq > 0.0f ? sqrtf(sq) : 0.0f;

        const float e = si + dj + nrm * coef * (float)adj[grow * NN + j];
        const float a = e * (float)mask[grow * NN + j];

        // --- softmax over 256 lanes: butterfly + one LDS combine ---
        float m = a;
        #pragma unroll
        for (int off = 32; off > 0; off >>= 1) m = fmaxf(m, __shfl_xor(m, off));
        if (lane == 0) redm[wave] = m;
        __syncthreads();
        const float rowmax = fmaxf(fmaxf(redm[0], redm[1]),
                                   fmaxf(redm[2], redm[3]));
        const float ex = __expf(a - rowmax);

        float ssum = ex;
        #pragma unroll
        for (int off = 32; off > 0; off >>= 1) ssum += __shfl_xor(ssum, off);
        if (lane == 0) reds[wave] = ssum;
        __syncthreads();
        const float inv = 1.0f / (reds[0] + reds[1] + reds[2] + reds[3]);

        out[grow * NN + j] = ex * inv;
        __syncthreads();                   // protect redm/reds for next row
    }
}

extern "C" void kernel_launch(void* const* d_in, const int* in_sizes, int n_in,
                              void* d_out, int out_size, void* d_ws, size_t ws_size,
                              hipStream_t stream) {
    const float* src    = (const float*)d_in[0];
    const int*   adj    = (const int*)  d_in[1];
    const int*   mask   = (const int*)  d_in[2];
    const float* W_lin  = (const float*)d_in[3];
    const float* a_src  = (const float*)d_in[4];
    const float* a_dst  = (const float*)d_in[5];
    const float* W_edge = (const float*)d_in[6];
    const float* a_edge = (const float*)d_in[7];
    float* out = (float*)d_out;
    float* sd  = (float*)d_ws;   // 2*BN + 1 floats

    attn_sd_kernel<<<BN / 8 + 1, 256, 0, stream>>>(src, W_lin, a_src, a_dst,
                                                   W_edge, a_edge, sd);
    attn_row_kernel<<<BN / 4, 256, 0, stream>>>(src, adj, mask, sd, out);
}